// Round 9
// baseline (27.908 us; speedup 1.0000x reference)
//
#include <hip/hip_runtime.h>

// out[b,d] = sum_c w[b,c] * f[idx[b,c,0],d] * f[idx[b,c,1],d]   (w==0 -> padding, tail-contiguous)
// fallback: out[b,:] = f[target_nodes[b],:] when has_edge[b] <= 0
//
// Round 8 = round-6 structure (best: 19.8us) + bf16 feature compression:
//  - pass 1: features f32 -> bf16 (RNE) into d_ws (12.8 MB)
//  - pass 2: identical branch-free gather loop, but each gathered row is 256B
//    (uint2 = 4 bf16 per lane) instead of 512B -> halves gather bytes/lines.
//  - math stays fp32 (unpack bf16 by bit-shift); fallback row uses fp32 features.
//  - keeps: XCD contiguous-chunk swizzle, 2 rows/wave, counted loop.
//  - if ws_size is too small for the bf16 table, falls back to the f32 kernel.

typedef float vfloat4 __attribute__((ext_vector_type(4)));

__device__ __forceinline__ unsigned short f2bf_rne(float x) {
    unsigned u = __float_as_uint(x);
    u += 0x7fffu + ((u >> 16) & 1u);
    return (unsigned short)(u >> 16);
}

__device__ __forceinline__ vfloat4 bf2f4(uint2 v) {
    vfloat4 r;
    r.x = __uint_as_float(v.x << 16);
    r.y = __uint_as_float(v.x & 0xffff0000u);
    r.z = __uint_as_float(v.y << 16);
    r.w = __uint_as_float(v.y & 0xffff0000u);
    return r;
}

__global__ __launch_bounds__(256) void convert_bf16_kernel(
    const float* __restrict__ f, uint2* __restrict__ o, int n4)
{
    const int i = blockIdx.x * 256 + threadIdx.x;
    if (i >= n4) return;
    const vfloat4 v = ((const vfloat4*)f)[i];
    uint2 p;
    p.x = (unsigned)f2bf_rne(v.x) | ((unsigned)f2bf_rne(v.y) << 16);
    p.y = (unsigned)f2bf_rne(v.z) | ((unsigned)f2bf_rne(v.w) << 16);
    o[i] = p;
}

template <bool BF16>
__global__ __launch_bounds__(256) void tmp_aggregate_kernel(
    const float*  __restrict__ features,      // [N, 128] fp32
    const uint2*  __restrict__ f16,           // [N, 32]  bf16-packed (BF16 path)
    const int*    __restrict__ target_nodes,  // [B]
    const int*    __restrict__ comb_idx,      // [B, cmax, 2]
    const float*  __restrict__ comb_w,        // [B, cmax]
    const float*  __restrict__ has_edge,      // [B]
    float*        __restrict__ out,           // [B, 128]
    int B, int cmax)
{
    // --- XCD-aware bijective swizzle (contiguous chunk per XCD) ---
    const int nwg = gridDim.x;
    const int xcd = blockIdx.x & 7;
    const int j   = blockIdx.x >> 3;
    const int q   = nwg >> 3, r = nwg & 7;
    const int lb  = (xcd < r ? xcd * (q + 1) : r * (q + 1) + (xcd - r) * q) + j;

    const int lane    = threadIdx.x & 63;
    const int wave    = __builtin_amdgcn_readfirstlane((int)(threadIdx.x >> 6));
    const int sub     = lane & 31;            // lane within half-wave
    const int half    = lane >> 5;            // 0 -> row b0, 1 -> row b1
    const int rowbase = (lb * 4 + wave) * 2;
    const int b       = rowbase + half;
    if (rowbase >= B) return;                 // B even; both rows valid together

    const vfloat4* __restrict__ f4 = (const vfloat4*)features;
    const long base = (long)b * cmax;

    // --- per-row live-combo count (w != 0), padding is tail-contiguous ---
    int cnt = 0;
    for (int c0 = 0; c0 < cmax; c0 += 32) {
        const int c = c0 + sub;
        const float w = (c < cmax) ? comb_w[base + c] : 0.0f;
        const unsigned long long m = __ballot(w != 0.0f);
        cnt += __popc((unsigned int)(m >> (half * 32)));
        const bool tail0 = ((unsigned int)(m      ) != 0xffffffffu);
        const bool tail1 = ((unsigned int)(m >> 32) != 0xffffffffu);
        if (tail0 && tail1) break;            // both rows found their tail
    }

    // wave-uniform loop bound = max over the two half-waves
    const int cnt_other = __shfl(cnt, lane ^ 32);
    const int loop_n = __builtin_amdgcn_readfirstlane(cnt > cnt_other ? cnt : cnt_other);

    const int tnode = target_nodes[b];
    const vfloat4 ft = f4[(long)tnode * 32 + sub];   // fp32 fallback row

    // --- branch-free main loop: 2 rows in flight per wave ---
    vfloat4 acc = {0.f, 0.f, 0.f, 0.f};
    const int2* __restrict__ idx2 = (const int2*)comb_idx;

    #pragma unroll 4
    for (int c = 0; c < loop_n; ++c) {
        const float w  = comb_w[base + c];            // broadcast within half-wave
        const int2  ix = idx2[base + c];
        vfloat4 x, y;
        if (BF16) {
            x = bf2f4(f16[(long)ix.x * 32 + sub]);    // 256B/row gathers
            y = bf2f4(f16[(long)ix.y * 32 + sub]);
        } else {
            x = f4[(long)ix.x * 32 + sub];            // 512B/row gathers
            y = f4[(long)ix.y * 32 + sub];
        }
        acc.x = fmaf(w * x.x, y.x, acc.x);
        acc.y = fmaf(w * x.y, y.y, acc.y);
        acc.z = fmaf(w * x.z, y.z, acc.z);
        acc.w = fmaf(w * x.w, y.w, acc.w);
    }

    const bool fb = !(has_edge[b] > 0.f);
    acc.x = fb ? ft.x : acc.x;
    acc.y = fb ? ft.y : acc.y;
    acc.z = fb ? ft.z : acc.z;
    acc.w = fb ? ft.w : acc.w;

    __builtin_nontemporal_store(acc, &((vfloat4*)out)[(long)b * 32 + sub]);
}

extern "C" void kernel_launch(void* const* d_in, const int* in_sizes, int n_in,
                              void* d_out, int out_size, void* d_ws, size_t ws_size,
                              hipStream_t stream) {
    const float* features     = (const float*)d_in[0];
    const int*   target_nodes = (const int*)d_in[1];
    const int*   comb_idx     = (const int*)d_in[2];
    const float* comb_w       = (const float*)d_in[3];
    const float* has_edge     = (const float*)d_in[4];
    float*       out          = (float*)d_out;

    const int nf   = in_sizes[0];                 // N*D = 6.4M
    const int B    = in_sizes[1];                 // 16384
    const int cmax = in_sizes[2] / (B * 2);       // combos per row (padded)

    const int rows_per_block = 8;                 // 4 waves x 2 rows
    const int grid = (B + rows_per_block - 1) / rows_per_block;

    const size_t need = (size_t)nf * 2;           // bf16 table bytes
    if (ws_size >= need) {
        uint2* f16 = (uint2*)d_ws;
        const int n4 = nf / 4;
        convert_bf16_kernel<<<(n4 + 255) / 256, 256, 0, stream>>>(features, f16, n4);
        tmp_aggregate_kernel<true><<<grid, 256, 0, stream>>>(
            features, f16, target_nodes, comb_idx, comb_w, has_edge, out, B, cmax);
    } else {
        tmp_aggregate_kernel<false><<<grid, 256, 0, stream>>>(
            features, (const uint2*)nullptr, target_nodes, comb_idx, comb_w, has_edge,
            out, B, cmax);
    }
}

// Round 10
// 18.048 us; speedup vs baseline: 1.5464x; 1.5464x over previous
//
#include <hip/hip_runtime.h>

// out[b,d] = sum_c w[b,c] * f[idx[b,c,0],d] * f[idx[b,c,1],d]   (w==0 -> padding, tail-contiguous)
// fallback: out[b,:] = f[target_nodes[b],:] when has_edge[b] <= 0
//
// Round 9 = round-6 champion (19.8us) + register-resident w/idx:
//  - per-row comb_w / comb_idx preloaded into registers (lane sub holds combos
//    sub and sub+32; covers cmax <= 64), broadcast per iteration via __shfl
//    (ds_bpermute -> LDS pipe). Inner loop VMEM ops drop 4 -> 2 (gathers only).
//  - ballot count now register-only; 32-bit gather address math.
//  - keeps: float4 lane, 2 rows/wave, XCD contiguous-chunk swizzle, counted loop.
//  - cmax > 64 falls back to the round-6 kernel (memory w/idx loads).

typedef float vfloat4 __attribute__((ext_vector_type(4)));

template <bool REG_WIDX>
__global__ __launch_bounds__(256) void tmp_aggregate_kernel(
    const float*  __restrict__ features,      // [N, 128]
    const int*    __restrict__ target_nodes,  // [B]
    const int*    __restrict__ comb_idx,      // [B, cmax, 2]
    const float*  __restrict__ comb_w,        // [B, cmax]
    const float*  __restrict__ has_edge,      // [B]
    float*        __restrict__ out,           // [B, 128]
    int B, int cmax)
{
    // --- XCD-aware bijective swizzle (contiguous chunk per XCD) ---
    const int nwg = gridDim.x;
    const int xcd = blockIdx.x & 7;
    const int jj  = blockIdx.x >> 3;
    const int q   = nwg >> 3, r = nwg & 7;
    const int lb  = (xcd < r ? xcd * (q + 1) : r * (q + 1) + (xcd - r) * q) + jj;

    const int lane    = threadIdx.x & 63;
    const int wave    = __builtin_amdgcn_readfirstlane((int)(threadIdx.x >> 6));
    const int sub     = lane & 31;            // lane within half-wave
    const int half    = lane >> 5;            // 0 -> row b0, 1 -> row b1
    const int rowbase = (lb * 4 + wave) * 2;
    const int b       = rowbase + half;
    if (rowbase >= B) return;                 // B even; both rows valid together

    const vfloat4* __restrict__ f4   = (const vfloat4*)features;
    const int2*    __restrict__ idx2 = (const int2*)comb_idx;
    const long base = (long)b * cmax;

    const int tnode = target_nodes[b];
    const vfloat4 ft = f4[(tnode << 5) + sub];

    vfloat4 acc = {0.f, 0.f, 0.f, 0.f};

    if (REG_WIDX) {
        // --- preload w/idx into registers (covers cmax <= 64) ---
        const bool v0 = (sub < cmax), v1 = (sub + 32 < cmax);
        const float w0 = v0 ? comb_w[base + sub]      : 0.f;
        const float w1 = v1 ? comb_w[base + sub + 32] : 0.f;
        const int2  i0 = v0 ? idx2[base + sub]        : make_int2(0, 0);
        const int2  i1 = v1 ? idx2[base + sub + 32]   : make_int2(0, 0);

        // --- register-only live-combo count (nonzero prefix, tail-contiguous) ---
        const unsigned long long m0 = __ballot(w0 != 0.f);
        const unsigned long long m1 = __ballot(w1 != 0.f);
        const int cnt = __popc((unsigned)(m0 >> (half * 32)))
                      + __popc((unsigned)(m1 >> (half * 32)));
        const int cnt_other = __shfl(cnt, lane ^ 32);
        const int loop_n = __builtin_amdgcn_readfirstlane(cnt > cnt_other ? cnt : cnt_other);

        // --- main loop: VMEM = 2 gathers only; w/idx via LDS-pipe shuffles ---
        #pragma unroll 4
        for (int c = 0; c < loop_n; ++c) {
            const int src = half * 32 + (c & 31);
            const float w   = __shfl(c < 32 ? w0   : w1,   src);
            const int   ixx = __shfl(c < 32 ? i0.x : i1.x, src);
            const int   ixy = __shfl(c < 32 ? i0.y : i1.y, src);
            const vfloat4 x = f4[(ixx << 5) + sub];
            const vfloat4 y = f4[(ixy << 5) + sub];
            acc.x = fmaf(w * x.x, y.x, acc.x);
            acc.y = fmaf(w * x.y, y.y, acc.y);
            acc.z = fmaf(w * x.z, y.z, acc.z);
            acc.w = fmaf(w * x.w, y.w, acc.w);
        }
    } else {
        // --- fallback (round-6 path) for cmax > 64 ---
        int cnt = 0;
        for (int c0 = 0; c0 < cmax; c0 += 32) {
            const int c = c0 + sub;
            const float w = (c < cmax) ? comb_w[base + c] : 0.0f;
            const unsigned long long m = __ballot(w != 0.0f);
            cnt += __popc((unsigned)(m >> (half * 32)));
            const bool tail0 = ((unsigned)(m      ) != 0xffffffffu);
            const bool tail1 = ((unsigned)(m >> 32) != 0xffffffffu);
            if (tail0 && tail1) break;
        }
        const int cnt_other = __shfl(cnt, lane ^ 32);
        const int loop_n = __builtin_amdgcn_readfirstlane(cnt > cnt_other ? cnt : cnt_other);

        #pragma unroll 4
        for (int c = 0; c < loop_n; ++c) {
            const float w  = comb_w[base + c];
            const int2  ix = idx2[base + c];
            const vfloat4 x = f4[(ix.x << 5) + sub];
            const vfloat4 y = f4[(ix.y << 5) + sub];
            acc.x = fmaf(w * x.x, y.x, acc.x);
            acc.y = fmaf(w * x.y, y.y, acc.y);
            acc.z = fmaf(w * x.z, y.z, acc.z);
            acc.w = fmaf(w * x.w, y.w, acc.w);
        }
    }

    const bool fb = !(has_edge[b] > 0.f);
    acc.x = fb ? ft.x : acc.x;
    acc.y = fb ? ft.y : acc.y;
    acc.z = fb ? ft.z : acc.z;
    acc.w = fb ? ft.w : acc.w;

    __builtin_nontemporal_store(acc, &((vfloat4*)out)[(b << 5) + sub]);
}

extern "C" void kernel_launch(void* const* d_in, const int* in_sizes, int n_in,
                              void* d_out, int out_size, void* d_ws, size_t ws_size,
                              hipStream_t stream) {
    const float* features     = (const float*)d_in[0];
    const int*   target_nodes = (const int*)d_in[1];
    const int*   comb_idx     = (const int*)d_in[2];
    const float* comb_w       = (const float*)d_in[3];
    const float* has_edge     = (const float*)d_in[4];
    float*       out          = (float*)d_out;

    const int B    = in_sizes[1];                 // 16384
    const int cmax = in_sizes[2] / (B * 2);       // combos per row (padded)

    const int rows_per_block = 8;                 // 4 waves x 2 rows
    const int grid = (B + rows_per_block - 1) / rows_per_block;

    if (cmax <= 64) {
        tmp_aggregate_kernel<true><<<grid, 256, 0, stream>>>(
            features, target_nodes, comb_idx, comb_w, has_edge, out, B, cmax);
    } else {
        tmp_aggregate_kernel<false><<<grid, 256, 0, stream>>>(
            features, target_nodes, comb_idx, comb_w, has_edge, out, B, cmax);
    }
}